// Round 1
// baseline (233.760 us; speedup 1.0000x reference)
//
#include <hip/hip_runtime.h>
#include <cstdint>
#include <cstddef>

#define N_COLS 4096
#define TPB 256
#define NCOPY 16
#define HSTRIDE 257   // 257 to spread the 16 copies of a hot bin across banks

// --- kernel 1: boost factors, double-precision exp rounded to fp32 ---
__global__ void boost_kernel(const float* __restrict__ dc,
                             const int* __restrict__ kp,
                             float* __restrict__ bf) {
    int i = blockIdx.x * blockDim.x + threadIdx.x;
    if (i < N_COLS) {
        float td = (float)kp[0] / (float)N_COLS;   // float32(k)/float32(n), like ref
        float arg = td - dc[i];                    // fp32 subtract, like ref
        bf[i] = (float)exp((double)arg);           // ~correctly-rounded fp32 exp
    }
}

__device__ __forceinline__ uint32_t orderable(float f) {
    uint32_t u = __float_as_uint(f);
    // monotone bijection: float order == unsigned order
    return (u & 0x80000000u) ? ~u : (u | 0x80000000u);
}

// one block per row; 16 elements per thread held in registers
__global__ __launch_bounds__(TPB) void kwinner_kernel(
    const float* __restrict__ x, const float* __restrict__ bf,
    const int* __restrict__ kp, float* __restrict__ out)
{
    __shared__ uint32_t s_hist[NCOPY * HSTRIDE];
    __shared__ uint32_t s_cnt[256];
    __shared__ uint32_t s_sel;

    const int tid = threadIdx.x;
    const size_t row = blockIdx.x;
    const float4* xr = (const float4*)(x + row * (size_t)N_COLS);
    const float4* br = (const float4*)bf;
    float4* orow = (float4*)(out + row * (size_t)N_COLS);

    float4 xv[4];
    uint32_t u[16];

    #pragma unroll
    for (int j = 0; j < 4; ++j) {
        float4 v = xr[tid + j * TPB];
        float4 b = br[tid + j * TPB];
        xv[j] = v;
        u[j * 4 + 0] = orderable(v.x * b.x);
        u[j * 4 + 1] = orderable(v.y * b.y);
        u[j * 4 + 2] = orderable(v.z * b.z);
        u[j * 4 + 3] = orderable(v.w * b.w);
    }

    uint32_t rem = (uint32_t)kp[0];   // rank (1-indexed) of element we seek
    uint32_t prefix = 0;
    const uint32_t pmasks[4] = {0u, 0xFF000000u, 0xFFFF0000u, 0xFFFFFF00u};

    for (int pass = 0; pass < 4; ++pass) {
        const int shift = 24 - pass * 8;
        // clear histograms
        for (int i = tid; i < NCOPY * HSTRIDE; i += TPB) s_hist[i] = 0;
        __syncthreads();

        const uint32_t pm = pmasks[pass];
        const uint32_t base = (uint32_t)(tid & (NCOPY - 1)) * HSTRIDE;
        #pragma unroll
        for (int e = 0; e < 16; ++e) {
            uint32_t uu = u[e];
            if (((uu ^ prefix) & pm) == 0u) {
                atomicAdd(&s_hist[base + ((uu >> shift) & 255u)], 1u);
            }
        }
        __syncthreads();

        // per-bin totals across the 16 copies
        uint32_t c = 0;
        #pragma unroll
        for (int cc = 0; cc < NCOPY; ++cc) c += s_hist[cc * HSTRIDE + tid];
        s_cnt[tid] = c;
        __syncthreads();

        // wave 0: suffix-scan 256 bins, pick largest digit d with S[d] >= rem
        if (tid < 64) {
            uint4 v = ((const uint4*)s_cnt)[tid];
            uint32_t s3 = v.w;
            uint32_t s2 = v.z + s3;
            uint32_t s1 = v.y + s2;
            uint32_t s0 = v.x + s1;
            uint32_t T = s0;
            #pragma unroll
            for (int off = 1; off < 64; off <<= 1) {
                uint32_t t = (uint32_t)__shfl_down((int)T, off, 64);
                if (tid + off < 64) T += t;
            }
            uint32_t Tex = T - s0;                // sum over lanes > tid
            uint32_t S0 = Tex + s0, S1 = Tex + s1, S2 = Tex + s2, S3 = Tex + s3;
            int b = -1; uint32_t sn = 0;
            if (S3 >= rem)      { b = 3; sn = S3 - v.w; }
            else if (S2 >= rem) { b = 2; sn = S2 - v.z; }
            else if (S1 >= rem) { b = 1; sn = S1 - v.y; }
            else if (S0 >= rem) { b = 0; sn = S0 - v.x; }
            uint32_t packed = (b >= 0)
                ? (((uint32_t)(4 * tid + b + 1) << 16) | sn)   // sn <= 408 fits 16b
                : 0u;
            #pragma unroll
            for (int off = 1; off < 64; off <<= 1) {
                uint32_t o = (uint32_t)__shfl_xor((int)packed, off, 64);
                packed = packed > o ? packed : o;
            }
            if (tid == 0) s_sel = packed;
        }
        __syncthreads();

        uint32_t packed = s_sel;
        uint32_t d = (packed >> 16) - 1u;
        uint32_t sn = packed & 0xFFFFu;
        rem -= sn;                 // uniform across block
        prefix |= d << shift;
    }

    // prefix == exact bit pattern of the k-th largest boosted value
    const uint32_t thr = prefix;
    #pragma unroll
    for (int j = 0; j < 4; ++j) {
        float4 v = xv[j];
        float4 o;
        o.x = (u[j * 4 + 0] >= thr) ? v.x : 0.0f;
        o.y = (u[j * 4 + 1] >= thr) ? v.y : 0.0f;
        o.z = (u[j * 4 + 2] >= thr) ? v.z : 0.0f;
        o.w = (u[j * 4 + 3] >= thr) ? v.w : 0.0f;
        orow[tid + j * TPB] = o;
    }
}

extern "C" void kernel_launch(void* const* d_in, const int* in_sizes, int n_in,
                              void* d_out, int out_size, void* d_ws, size_t ws_size,
                              hipStream_t stream) {
    const float* x  = (const float*)d_in[0];
    const float* dc = (const float*)d_in[1];
    const int*   kp = (const int*)d_in[2];
    float* out = (float*)d_out;
    float* bf  = (float*)d_ws;                 // 4096 floats of scratch

    const int n    = in_sizes[1];              // 4096
    const int rows = in_sizes[0] / n;          // 8192

    boost_kernel<<<(n + TPB - 1) / TPB, TPB, 0, stream>>>(dc, kp, bf);
    kwinner_kernel<<<rows, TPB, 0, stream>>>(x, bf, kp, out);
}